// Round 8
// baseline (188.406 us; speedup 1.0000x reference)
//
#include <hip/hip_runtime.h>
#include <hip/hip_bf16.h>

#define T_TASKS 16
#define S_SUP   2048
#define Q_QRY   2048
#define D_IN    256
#define H_HID   512
#define D_EMB   128
#define N_WAY   64
#define NCHUNK  16
#define CHUNK   128   // S_SUP / NCHUNK
#define QB      64    // queries per block in query_mfma
#define PROWS   16384 // rows per embed pass

typedef unsigned short ushortT;
typedef unsigned int uintT;
using bf16x8 = __attribute__((ext_vector_type(8))) short;
using f32x4  = __attribute__((ext_vector_type(4))) float;

__device__ __forceinline__ ushortT f2b(float f) {
    uintT u = __builtin_bit_cast(uintT, f);
    uintT r = u + 0x7FFFu + ((u >> 16) & 1u);   // round-to-nearest-even
    return (ushortT)(r >> 16);
}
__device__ __forceinline__ float b2f(ushortT h) {
    return __builtin_bit_cast(float, (uintT)h << 16);
}
__device__ __forceinline__ uintT pk2(float a, float b) {
    return (uintT)f2b(a) | ((uintT)f2b(b) << 16);
}

// ---------------------------------------------------------------------------
// Convert weights fp32 -> bf16, transposed to [N][K].
// ---------------------------------------------------------------------------
__global__ __launch_bounds__(256) void convert_weights(
    const float* __restrict__ W1, const float* __restrict__ W2,
    ushortT* __restrict__ W1t, ushortT* __restrict__ W2t)
{
    int i = blockIdx.x * 256 + threadIdx.x;
    if (i < D_IN * H_HID) {              // W1 [256][512] -> W1t [512][256]
        int k = i >> 9, n = i & 511;
        W1t[n * D_IN + k] = f2b(W1[i]);
    }
    if (i < H_HID * D_EMB) {             // W2 [512][128] -> W2t [128][512]
        int k = i >> 7, n = i & 127;
        W2t[n * H_HID + k] = f2b(W2[i]);
    }
}

// ---------------------------------------------------------------------------
// G1 (swapped): h[r][c] = relu(x@W1+b1), 16384 rows per pass.
// D1[c][r] = W1t . x^T : A = W1t (row c, k contig), B = x-frag (col r, k contig).
// C/D: lane holds c = c0+g*4+reg (4 CONSECUTIVE c) for one r  ->  b64 h-writes.
// 512 thr = 8 waves = 4 cgroups x 2 rgroups; 64 rows/block; xs 32 KiB LDS.
// ---------------------------------------------------------------------------
__global__ __launch_bounds__(512) void g1_swapped(
    const float* __restrict__ x, const ushortT* __restrict__ W1t,
    const float* __restrict__ b1, ushortT* __restrict__ h)
{
    __shared__ ushortT xs[64 * D_IN];   // 32 KiB, XOR-swizzled

    const int tid  = threadIdx.x;
    const int wid  = tid >> 6;
    const int lane = tid & 63;
    const int lr   = lane & 15;
    const int g    = lane >> 4;
    const int cg   = wid >> 1;          // 0..3: ct in cg*8 .. cg*8+7
    const int rg   = wid & 1;           // 0..1: rows rg*32 .. rg*32+31
    const long rowbase = (long)blockIdx.x * 64;

    // ---- stage x tile (64x256) as bf16 swizzled (v2-proven pattern) -----
    #pragma unroll
    for (int i = 0; i < 4; ++i) {
        int ci   = tid + 512 * i;
        int row  = ci >> 5;
        int col8 = (ci & 31) << 3;
        const float4* p = (const float4*)(x + (rowbase + row) * D_IN + col8);
        float4 a = p[0], b = p[1];
        uint4 v;
        v.x = pk2(a.x, a.y);
        v.y = pk2(a.z, a.w);
        v.z = pk2(b.x, b.y);
        v.w = pk2(b.z, b.w);
        int idx = (row << 8) + col8;
        idx ^= (row & 7) << 3;
        *(uint4*)&xs[idx] = v;
    }
    __syncthreads();

    // ---- cache x B-frags in regs: bfc[i][kk], i = 16-row subtile --------
    bf16x8 bfc[2][8];
    #pragma unroll
    for (int i = 0; i < 2; ++i) {
        int rl = rg * 32 + i * 16 + lr;
        #pragma unroll
        for (int kk = 0; kk < 8; ++kk) {
            int idx = (rl * D_IN + kk * 32 + g * 8) ^ ((rl & 7) << 3);
            bfc[i][kk] = *(const bf16x8*)&xs[idx];
        }
    }

    // ---- c-tiles: D1 = W1t . x^T, relu, pack, b64 store -----------------
    #pragma unroll
    for (int ct8 = 0; ct8 < 8; ++ct8) {
        int c0 = (cg * 8 + ct8) * 16;
        float4 bv = *(const float4*)&b1[c0 + g * 4];
        f32x4 acc0 = {bv.x, bv.y, bv.z, bv.w};
        f32x4 acc1 = acc0;
        const ushortT* w1p = W1t + (c0 + lr) * D_IN + g * 8;
        #pragma unroll
        for (int kk = 0; kk < 8; ++kk) {
            bf16x8 af = *(const bf16x8*)(w1p + kk * 32);
            acc0 = __builtin_amdgcn_mfma_f32_16x16x32_bf16(af, bfc[0][kk], acc0, 0, 0, 0);
            acc1 = __builtin_amdgcn_mfma_f32_16x16x32_bf16(af, bfc[1][kk], acc1, 0, 0, 0);
        }
        // lane: c = c0+g*4+{0..3}, r = rowbase + rg*32 + i*16 + lr
        uint2 u0, u1;
        u0.x = pk2(fmaxf(acc0[0], 0.f), fmaxf(acc0[1], 0.f));
        u0.y = pk2(fmaxf(acc0[2], 0.f), fmaxf(acc0[3], 0.f));
        u1.x = pk2(fmaxf(acc1[0], 0.f), fmaxf(acc1[1], 0.f));
        u1.y = pk2(fmaxf(acc1[2], 0.f), fmaxf(acc1[3], 0.f));
        long r0 = rowbase + rg * 32 + lr;
        *(uint2*)&h[(r0)      * H_HID + c0 + g * 4] = u0;
        *(uint2*)&h[(r0 + 16) * H_HID + c0 + g * 4] = u1;
    }
}

// ---------------------------------------------------------------------------
// G2 (swapped, LDS-free): out[r][d] = h@W2 + b2, bf16 out (se/qe).
// D2[d][r] = W2t . h^T : A = W2t (row d, k contig), B = h-frag (col r, k contig).
// 256 thr = 4 waves = 2 dgroups(64 d) x 2 rgroups(32 rows); 64 rows/block.
// ---------------------------------------------------------------------------
__global__ __launch_bounds__(256) void g2_swapped(
    const ushortT* __restrict__ h, const ushortT* __restrict__ W2t,
    const float* __restrict__ b2, ushortT* __restrict__ out)
{
    const int tid  = threadIdx.x;
    const int wid  = tid >> 6;
    const int lane = tid & 63;
    const int lr   = lane & 15;
    const int g    = lane >> 4;
    const int dtg  = wid >> 1;          // 0..1: d-strip of 64
    const int rtg  = wid & 1;           // 0..1: 32-row group
    const long r0  = (long)blockIdx.x * 64 + rtg * 32;

    f32x4 acc[4][2];
    #pragma unroll
    for (int dtl = 0; dtl < 4; ++dtl) {
        float4 bv = *(const float4*)&b2[dtg * 64 + dtl * 16 + g * 4];
        f32x4 a = {bv.x, bv.y, bv.z, bv.w};
        acc[dtl][0] = a; acc[dtl][1] = a;
    }

    const ushortT* hp0 = h + (r0 + lr)      * H_HID + g * 8;
    const ushortT* hp1 = h + (r0 + 16 + lr) * H_HID + g * 8;
    #pragma unroll
    for (int kk = 0; kk < 16; ++kk) {
        bf16x8 bf0 = *(const bf16x8*)(hp0 + kk * 32);
        bf16x8 bf1 = *(const bf16x8*)(hp1 + kk * 32);
        #pragma unroll
        for (int dtl = 0; dtl < 4; ++dtl) {
            bf16x8 af = *(const bf16x8*)(W2t + (dtg * 64 + dtl * 16 + lr) * H_HID + kk * 32 + g * 8);
            acc[dtl][0] = __builtin_amdgcn_mfma_f32_16x16x32_bf16(af, bf0, acc[dtl][0], 0, 0, 0);
            acc[dtl][1] = __builtin_amdgcn_mfma_f32_16x16x32_bf16(af, bf1, acc[dtl][1], 0, 0, 0);
        }
    }

    // epilogue: d = dtg*64+dtl*16+g*4+{0..3}, r = r0 + i*16 + lr -> b64 writes
    #pragma unroll
    for (int dtl = 0; dtl < 4; ++dtl)
        #pragma unroll
        for (int i = 0; i < 2; ++i) {
            uint2 u;
            u.x = pk2(acc[dtl][i][0], acc[dtl][i][1]);
            u.y = pk2(acc[dtl][i][2], acc[dtl][i][3]);
            *(uint2*)&out[(r0 + i * 16 + lr) * D_EMB + dtg * 64 + dtl * 16 + g * 4] = u;
        }
}

// ---------------------------------------------------------------------------
// Proto phase 1: block = (t, chunk of 128 rows), two LDS accumulation streams.
// ---------------------------------------------------------------------------
__global__ __launch_bounds__(256) void proto_partial(
    const ushortT* __restrict__ se, const int* __restrict__ ids,
    float* __restrict__ psum, int* __restrict__ pcnt)
{
    __shared__ float acc[2][N_WAY][D_EMB];  // 64 KiB
    __shared__ int idbuf[CHUNK];

    const int tid  = threadIdx.x;
    const int t    = blockIdx.x >> 4;
    const int ch   = blockIdx.x & 15;
    const int d    = tid & 127;
    const int half = tid >> 7;

    #pragma unroll
    for (int i = 0; i < 64; ++i)
        ((float*)acc)[tid + 256 * i] = 0.0f;
    if (tid < CHUNK) idbuf[tid] = ids[t * S_SUP + ch * CHUNK + tid];
    __syncthreads();

    const ushortT* sb = se + ((long)t * S_SUP + ch * CHUNK) * D_EMB;
    #pragma unroll 4
    for (int s = 0; s < 64; ++s) {
        int row = half * 64 + s;
        int c = idbuf[row];
        acc[half][c][d] += b2f(sb[(long)row * D_EMB + d]);
    }
    __syncthreads();

    float* pb = psum + (long)blockIdx.x * N_WAY * D_EMB;
    #pragma unroll
    for (int i = 0; i < 32; ++i) {
        int idx = tid + 256 * i;
        pb[idx] = acc[0][idx >> 7][idx & 127] + acc[1][idx >> 7][idx & 127];
    }
    if (tid < N_WAY) {
        int cnt = 0;
        #pragma unroll 8
        for (int s = 0; s < CHUNK; ++s) cnt += (idbuf[s] == tid);
        pcnt[blockIdx.x * N_WAY + tid] = cnt;
    }
}

__global__ __launch_bounds__(256) void proto_reduce(
    const float* __restrict__ psum, const int* __restrict__ pcnt,
    float* __restrict__ protos)
{
    int idx = blockIdx.x * 256 + threadIdx.x;
    int t = idx >> 13;
    int cd = idx & 8191;
    int c = cd >> 7;

    float s = 0.0f;
    int cnt = 0;
    #pragma unroll
    for (int ch = 0; ch < NCHUNK; ++ch) {
        s   += psum[((long)(t * NCHUNK + ch)) * N_WAY * D_EMB + cd];
        cnt += pcnt[(t * NCHUNK + ch) * N_WAY + c];
    }
    protos[idx] = s / (float)(cnt > 0 ? cnt : 1);
}

// ---------------------------------------------------------------------------
// query_mfma: qe bf16 direct fragment loads.
// ---------------------------------------------------------------------------
__global__ __launch_bounds__(256) void query_mfma(
    const ushortT* __restrict__ qe, const float* __restrict__ qy,
    const float* __restrict__ protos_g, float* __restrict__ partials)
{
    __shared__ ushortT psA[N_WAY * D_EMB];       // [c][d] swizzled, 16 KiB
    __shared__ ushortT psT[D_EMB * N_WAY];       // [d][c] swizzled, 16 KiB
    __shared__ ushortT probs_s[4][16 * N_WAY];   // per-wave [q][c] swizzled, 8 KiB
    __shared__ float p2s[N_WAY];
    __shared__ float wloss[4];

    const int tid  = threadIdx.x;
    const int wave = tid >> 6;
    const int lane = tid & 63;
    const int lr   = lane & 15;
    const int lg   = lane >> 4;
    const int t    = blockIdx.x >> 5;        // 32 blocks per task
    const int qblk = blockIdx.x & 31;

    const float* pt = protos_g + (long)t * N_WAY * D_EMB;

    // ---- stage psA [c][d] bf16 swizzled + per-chunk sumsq for p2 --------
    float pp[4];
    #pragma unroll
    for (int i = 0; i < 4; ++i) {
        int ci = tid + 256 * i;
        int c = ci >> 4, col8 = (ci & 15) << 3;
        const float4* p = (const float4*)(pt + c * D_EMB + col8);
        float4 a = p[0], b = p[1];
        ushortT h0 = f2b(a.x), h1 = f2b(a.y), h2 = f2b(a.z), h3 = f2b(a.w);
        ushortT h4 = f2b(b.x), h5 = f2b(b.y), h6 = f2b(b.z), h7 = f2b(b.w);
        float ss = b2f(h0)*b2f(h0) + b2f(h1)*b2f(h1) + b2f(h2)*b2f(h2) + b2f(h3)*b2f(h3)
                 + b2f(h4)*b2f(h4) + b2f(h5)*b2f(h5) + b2f(h6)*b2f(h6) + b2f(h7)*b2f(h7);
        pp[i] = ss;
        uint4 v;
        v.x = (uintT)h0 | ((uintT)h1 << 16);
        v.y = (uintT)h2 | ((uintT)h3 << 16);
        v.z = (uintT)h4 | ((uintT)h5 << 16);
        v.w = (uintT)h6 | ((uintT)h7 << 16);
        int idx = c * D_EMB + col8;
        idx ^= (c & 7) << 3;
        *(uint4*)&psA[idx] = v;
    }
    #pragma unroll
    for (int off = 1; off < 16; off <<= 1) {
        #pragma unroll
        for (int i = 0; i < 4; ++i) pp[i] += __shfl_xor(pp[i], off);
    }
    if ((lane & 15) == 0) {
        int a = wave * 4 + (lane >> 4);
        #pragma unroll
        for (int i = 0; i < 4; ++i) p2s[a + 16 * i] = pp[i];
    }

    // ---- stage psT [d][c] bf16 swizzled ---------------------------------
    {
        int d  = wave * 32 + (lane & 31);
        int ch = lane >> 5;
        #pragma unroll
        for (int m = 0; m < 4; ++m) {
            ushortT hh[8];
            #pragma unroll
            for (int j = 0; j < 8; ++j)
                hh[j] = f2b(pt[(ch * 32 + m * 8 + j) * D_EMB + d]);
            uint4 v;
            v.x = (uintT)hh[0] | ((uintT)hh[1] << 16);
            v.y = (uintT)hh[2] | ((uintT)hh[3] << 16);
            v.z = (uintT)hh[4] | ((uintT)hh[5] << 16);
            v.w = (uintT)hh[6] | ((uintT)hh[7] << 16);
            int idx = d * N_WAY + ch * 32 + m * 8;
            idx ^= (d & 7) << 3;
            *(uint4*)&psT[idx] = v;
        }
    }
    __syncthreads();

    // ---- load qe rows as B-frags (bf16 direct), compute q2 --------------
    const long qrow = (long)t * Q_QRY + qblk * QB + wave * 16 + lr;
    bf16x8 bq[4];
    float q2 = 0.0f;
    #pragma unroll
    for (int kk = 0; kk < 4; ++kk) {
        bq[kk] = *(const bf16x8*)(qe + qrow * D_EMB + kk * 32 + lg * 8);
        #pragma unroll
        for (int j = 0; j < 8; ++j) {
            float v = b2f((ushortT)bq[kk][j]);
            q2 += v * v;
        }
    }
    q2 += __shfl_xor(q2, 16);
    q2 += __shfl_xor(q2, 32);

    // ---- qpT = protos . qe^T --------------------------------------------
    f32x4 acc[4];
    #pragma unroll
    for (int mt = 0; mt < 4; ++mt) { f32x4 z = {0,0,0,0}; acc[mt] = z; }
    #pragma unroll
    for (int kk = 0; kk < 4; ++kk) {
        #pragma unroll
        for (int mt = 0; mt < 4; ++mt) {
            int c = mt * 16 + lr;
            int idx = (c * D_EMB + kk * 32 + lg * 8) ^ ((c & 7) << 3);
            bf16x8 af = *(const bf16x8*)&psA[idx];
            acc[mt] = __builtin_amdgcn_mfma_f32_16x16x32_bf16(af, bq[kk], acc[mt], 0, 0, 0);
        }
    }

    // ---- dist -> in-register softmax over 64 classes --------------------
    float ev[4][4];
    float mx = -1e30f;
    #pragma unroll
    for (int mt = 0; mt < 4; ++mt) {
        #pragma unroll
        for (int r = 0; r < 4; ++r) {
            int c = mt * 16 + lg * 4 + r;
            float d2 = q2 + p2s[c] - 2.0f * acc[mt][r];
            float v = -sqrtf(fmaxf(d2, 0.0f));
            ev[mt][r] = v;
            mx = fmaxf(mx, v);
        }
    }
    mx = fmaxf(mx, __shfl_xor(mx, 16));
    mx = fmaxf(mx, __shfl_xor(mx, 32));
    float sum = 0.0f;
    #pragma unroll
    for (int mt = 0; mt < 4; ++mt)
        #pragma unroll
        for (int r = 0; r < 4; ++r) {
            float e = __expf(ev[mt][r] - mx);
            ev[mt][r] = e;
            sum += e;
        }
    sum += __shfl_xor(sum, 16);
    sum += __shfl_xor(sum, 32);
    float inv = 1.0f / sum;

    // ---- probs -> per-wave LDS tile [q][c] bf16 swizzled ----------------
    #pragma unroll
    for (int mt = 0; mt < 4; ++mt) {
        uintT lo = pk2(ev[mt][0] * inv, ev[mt][1] * inv);
        uintT hi = pk2(ev[mt][2] * inv, ev[mt][3] * inv);
        int idx = lr * N_WAY + ((mt * 16 + lg * 4) ^ ((lr & 7) << 3));
        uint2 v = {lo, hi};
        *(uint2*)&probs_s[wave][idx] = v;
    }

    // ---- pred = probs . protos ------------------------------------------
    f32x4 acc2[8];
    #pragma unroll
    for (int nt = 0; nt < 8; ++nt) { f32x4 z = {0,0,0,0}; acc2[nt] = z; }
    #pragma unroll
    for (int kk = 0; kk < 2; ++kk) {
        int idxa = lr * N_WAY + ((kk * 32 + lg * 8) ^ ((lr & 7) << 3));
        bf16x8 af = *(const bf16x8*)&probs_s[wave][idxa];
        #pragma unroll
        for (int nt = 0; nt < 8; ++nt) {
            int d = nt * 16 + lr;
            int idxb = (d * N_WAY + kk * 32 + lg * 8) ^ ((d & 7) << 3);
            bf16x8 bf = *(const bf16x8*)&psT[idxb];
            acc2[nt] = __builtin_amdgcn_mfma_f32_16x16x32_bf16(af, bf, acc2[nt], 0, 0, 0);
        }
    }

    // ---- fused squared-error loss ---------------------------------------
    float lossacc = 0.0f;
    const long qgbase = (long)t * Q_QRY + qblk * QB + wave * 16;
    #pragma unroll
    for (int r = 0; r < 4; ++r) {
        const float* yrow = qy + (qgbase + lg * 4 + r) * D_EMB;
        #pragma unroll
        for (int nt = 0; nt < 8; ++nt) {
            float diff = acc2[nt][r] - yrow[nt * 16 + lr];
            lossacc += diff * diff;
        }
    }
    #pragma unroll
    for (int off = 32; off >= 1; off >>= 1) lossacc += __shfl_xor(lossacc, off);
    if (lane == 0) wloss[wave] = lossacc;
    __syncthreads();
    if (tid == 0)
        partials[blockIdx.x] = wloss[0] + wloss[1] + wloss[2] + wloss[3];
}

// ---------------------------------------------------------------------------
// Final reduce: 512 partials -> meta_loss scalar
// ---------------------------------------------------------------------------
__global__ __launch_bounds__(256) void reduce_kernel(
    const float* __restrict__ partials, float* __restrict__ out)
{
    __shared__ float wsum[4];
    const int tid = threadIdx.x;
    float s = partials[tid] + partials[tid + 256];
    #pragma unroll
    for (int off = 32; off >= 1; off >>= 1) s += __shfl_xor(s, off);
    if ((tid & 63) == 0) wsum[tid >> 6] = s;
    __syncthreads();
    if (tid == 0) {
        const float inv = 1.0f / ((float)T_TASKS * Q_QRY * D_EMB);
        out[0] = (wsum[0] + wsum[1] + wsum[2] + wsum[3]) * inv;
    }
}

extern "C" void kernel_launch(void* const* d_in, const int* in_sizes, int n_in,
                              void* d_out, int out_size, void* d_ws, size_t ws_size,
                              hipStream_t stream)
{
    const float* support_x = (const float*)d_in[0];
    const int*   support_ids = (const int*)d_in[1];
    const float* query_x  = (const float*)d_in[2];
    const float* query_y  = (const float*)d_in[3];
    const float* W1 = (const float*)d_in[4];
    const float* b1 = (const float*)d_in[5];
    const float* W2 = (const float*)d_in[6];
    const float* b2 = (const float*)d_in[7];

    // ws layout (h region aliased with proto scratch, used only after embed):
    ushortT* se   = (ushortT*)d_ws;                          // 32768*128 bf16
    ushortT* qe   = se + (long)32768 * D_EMB;                // 32768*128 bf16
    ushortT* W1t  = qe + (long)32768 * D_EMB;                // 512*256 bf16
    ushortT* W2t  = W1t + H_HID * D_IN;                      // 128*512 bf16
    float* protos = (float*)(W2t + D_EMB * H_HID);           // 16*64*128 f32
    ushortT* h    = (ushortT*)(protos + T_TASKS * N_WAY * D_EMB); // 16384*512 bf16 (16MB)
    float* psum   = (float*)h;                               // alias: 256*64*128 f32
    int*   pcnt   = (int*)(psum + (long)256 * N_WAY * D_EMB);
    float* partials = (float*)(pcnt + 256 * N_WAY);          // 512 f32

    convert_weights<<<512, 256, 0, stream>>>(W1, W2, W1t, W2t);

    // 4 embed passes of 16384 rows: support halves then query halves
    for (int p = 0; p < 4; ++p) {
        const float* xsrc = ((p < 2) ? support_x : query_x) + (long)(p & 1) * PROWS * D_IN;
        ushortT* dst      = ((p < 2) ? se : qe) + (long)(p & 1) * PROWS * D_EMB;
        g1_swapped<<<PROWS / 64, 512, 0, stream>>>(xsrc, W1t, b1, h);
        g2_swapped<<<PROWS / 64, 256, 0, stream>>>(h, W2t, b2, dst);
    }

    proto_partial<<<T_TASKS * NCHUNK, 256, 0, stream>>>(se, support_ids, psum, pcnt);
    proto_reduce<<<512, 256, 0, stream>>>(psum, pcnt, protos);
    query_mfma<<<T_TASKS * (Q_QRY / QB), 256, 0, stream>>>(qe, query_y, protos, partials);
    reduce_kernel<<<1, 256, 0, stream>>>(partials, (float*)d_out);
}

// Round 10
// 178.861 us; speedup vs baseline: 1.0534x; 1.0534x over previous
//
#include <hip/hip_runtime.h>
#include <hip/hip_bf16.h>

#define T_TASKS 16
#define S_SUP   2048
#define Q_QRY   2048
#define D_IN    256
#define H_HID   512
#define D_EMB   128
#define N_WAY   64
#define NCHUNK  16
#define CHUNK   128   // S_SUP / NCHUNK
#define QB      64    // queries per block in query_mfma
#define BM4     64    // rows per block in embed_mfma4

typedef unsigned short ushortT;
typedef unsigned int uintT;
using bf16x8 = __attribute__((ext_vector_type(8))) short;
using f32x4  = __attribute__((ext_vector_type(4))) float;

__device__ __forceinline__ ushortT f2b(float f) {
    uintT u = __builtin_bit_cast(uintT, f);
    uintT r = u + 0x7FFFu + ((u >> 16) & 1u);   // round-to-nearest-even
    return (ushortT)(r >> 16);
}
__device__ __forceinline__ float b2f(ushortT h) {
    return __builtin_bit_cast(float, (uintT)h << 16);
}
// packed f32 pair -> bf16x2 (RTNE bit-twiddle, proven in all passing rounds)
__device__ __forceinline__ uintT pk2(float a, float b) {
    return (uintT)f2b(a) | ((uintT)f2b(b) << 16);
}

// ---------------------------------------------------------------------------
// Convert weights fp32 -> bf16, transposed to [N][K].
// ---------------------------------------------------------------------------
__global__ __launch_bounds__(256) void convert_weights(
    const float* __restrict__ W1, const float* __restrict__ W2,
    ushortT* __restrict__ W1t, ushortT* __restrict__ W2t)
{
    int i = blockIdx.x * 256 + threadIdx.x;
    if (i < D_IN * H_HID) {              // W1 [256][512] -> W1t [512][256]
        int k = i >> 9, n = i & 511;
        W1t[n * D_IN + k] = f2b(W1[i]);
    }
    if (i < H_HID * D_EMB) {             // W2 [512][128] -> W2t [128][512]
        int k = i >> 7, n = i & 127;
        W2t[n * H_HID + k] = f2b(W2[i]);
    }
}

// ---------------------------------------------------------------------------
// embed v4: fused, both GEMMs SWAPPED (D = W . x^T) so each lane's 4 C/D regs
// are 4 CONSECUTIVE output channels of one row -> b64 packed stores.
// 512 thr (8 waves), 64 rows/block, 64 KiB LDS (xs overlays hs), 1 dispatch.
// G1: waves = 4 cgroups(128 cols) x 2 rgroups(32 rows); x B-frags reg-cached.
// G2: waves = 2 dgroups(64 cols)  x 4 rgroups(16 rows); h B-frags from LDS.
// ---------------------------------------------------------------------------
__global__ __launch_bounds__(512, 4) void embed_mfma4(
    const float* __restrict__ xa, const float* __restrict__ xb,
    const ushortT* __restrict__ W1t, const float* __restrict__ b1,
    const ushortT* __restrict__ W2t, const float* __restrict__ b2,
    ushortT* __restrict__ outa, ushortT* __restrict__ outb)
{
    __shared__ ushortT hs[BM4 * H_HID];   // 64 KiB; xs overlays first 32 KiB
    ushortT* xs = hs;                     // [64][256] swizzled (dead before hs)

    const int tid  = threadIdx.x;
    const int wid  = tid >> 6;
    const int lane = tid & 63;
    const int lr   = lane & 15;
    const int g    = lane >> 4;
    const int bid  = blockIdx.x;
    const float*  x   = (bid < 512) ? xa : xb;
    ushortT*      out = (bid < 512) ? outa : outb;
    const long rowbase = (long)(bid & 511) * BM4;

    // ---- stage x tile (64x256) as bf16 swizzled -------------------------
    #pragma unroll
    for (int i = 0; i < 4; ++i) {
        int ci   = tid + 512 * i;        // 2048 chunks of 8 elems
        int row  = ci >> 5;
        int col8 = (ci & 31) << 3;
        const float4* p = (const float4*)(x + (rowbase + row) * D_IN + col8);
        float4 a = p[0], b = p[1];
        uint4 v;
        v.x = pk2(a.x, a.y);
        v.y = pk2(a.z, a.w);
        v.z = pk2(b.x, b.y);
        v.w = pk2(b.z, b.w);
        int idx = (row << 8) + col8;
        idx ^= (row & 7) << 3;
        *(uint4*)&xs[idx] = v;
    }
    __syncthreads();

    // ---- cache x B-frags in regs (xs dead afterwards) -------------------
    const int rg1 = wid & 1;             // G1 row-group: rows rg1*32 .. +31
    const int cg1 = wid >> 1;            // G1 col-group: cols cg1*128 .. +127
    bf16x8 bfc[2][8];
    #pragma unroll
    for (int i = 0; i < 2; ++i) {
        int rl = rg1 * 32 + i * 16 + lr;
        #pragma unroll
        for (int kk = 0; kk < 8; ++kk) {
            int idx = (rl << 8) + kk * 32 + g * 8;
            idx ^= (rl & 7) << 3;
            bfc[i][kk] = *(const bf16x8*)&xs[idx];
        }
    }
    __syncthreads();   // xs reads complete -> hs may overwrite

    // ---- G1: D1[c][r] = W1t . x^T, relu, b64 LDS stores -----------------
    #pragma unroll
    for (int ct8 = 0; ct8 < 8; ++ct8) {
        int c0 = cg1 * 128 + ct8 * 16;
        float4 bv = *(const float4*)&b1[c0 + g * 4];
        f32x4 acc0 = {bv.x, bv.y, bv.z, bv.w};
        f32x4 acc1 = acc0;
        const ushortT* w1p = W1t + (c0 + lr) * D_IN + g * 8;
        #pragma unroll
        for (int kk = 0; kk < 8; ++kk) {
            bf16x8 af = *(const bf16x8*)(w1p + kk * 32);
            acc0 = __builtin_amdgcn_mfma_f32_16x16x32_bf16(af, bfc[0][kk], acc0, 0, 0, 0);
            acc1 = __builtin_amdgcn_mfma_f32_16x16x32_bf16(af, bfc[1][kk], acc1, 0, 0, 0);
        }
        // lane: row r = rg1*32 + i*16 + lr, cols c0+g*4 .. +3 (consecutive)
        uint2 u0, u1;
        u0.x = pk2(fmaxf(acc0[0], 0.f), fmaxf(acc0[1], 0.f));
        u0.y = pk2(fmaxf(acc0[2], 0.f), fmaxf(acc0[3], 0.f));
        u1.x = pk2(fmaxf(acc1[0], 0.f), fmaxf(acc1[1], 0.f));
        u1.y = pk2(fmaxf(acc1[2], 0.f), fmaxf(acc1[3], 0.f));
        int r0 = rg1 * 32 + lr;
        int i0 = ((r0)      * H_HID + c0 + g * 4) ^ (((r0)      & 7) << 3);
        int i1 = ((r0 + 16) * H_HID + c0 + g * 4) ^ (((r0 + 16) & 7) << 3);
        *(uint2*)&hs[i0] = u0;
        *(uint2*)&hs[i1] = u1;
    }
    __syncthreads();

    // ---- G2: D2[d][r] = W2t . h^T, b64 global stores --------------------
    const int rg2 = wid & 3;             // rows rg2*16 .. +15
    const int dg2 = wid >> 2;            // cols dg2*64 .. +63
    bf16x8 bhf[16];
    {
        int rl = rg2 * 16 + lr;
        #pragma unroll
        for (int kk = 0; kk < 16; ++kk) {
            int idx = (rl * H_HID + kk * 32 + g * 8) ^ ((rl & 7) << 3);
            bhf[kk] = *(const bf16x8*)&hs[idx];
        }
    }
    #pragma unroll
    for (int dt = 0; dt < 4; ++dt) {
        int d0 = dg2 * 64 + dt * 16;
        float4 bv = *(const float4*)&b2[d0 + g * 4];
        f32x4 acc = {bv.x, bv.y, bv.z, bv.w};
        const ushortT* w2p = W2t + (d0 + lr) * H_HID + g * 8;
        #pragma unroll
        for (int kk = 0; kk < 16; ++kk) {
            bf16x8 af = *(const bf16x8*)(w2p + kk * 32);
            acc = __builtin_amdgcn_mfma_f32_16x16x32_bf16(af, bhf[kk], acc, 0, 0, 0);
        }
        uint2 u;
        u.x = pk2(acc[0], acc[1]);
        u.y = pk2(acc[2], acc[3]);
        long row = rowbase + rg2 * 16 + lr;
        *(uint2*)&out[row * D_EMB + d0 + g * 4] = u;
    }
}

// ---------------------------------------------------------------------------
// Proto phase 1: block = (t, chunk of 128 rows), two LDS accumulation streams.
// ---------------------------------------------------------------------------
__global__ __launch_bounds__(256) void proto_partial(
    const ushortT* __restrict__ se, const int* __restrict__ ids,
    float* __restrict__ psum, int* __restrict__ pcnt)
{
    __shared__ float acc[2][N_WAY][D_EMB];  // 64 KiB
    __shared__ int idbuf[CHUNK];

    const int tid  = threadIdx.x;
    const int t    = blockIdx.x >> 4;
    const int ch   = blockIdx.x & 15;
    const int d    = tid & 127;
    const int half = tid >> 7;

    #pragma unroll
    for (int i = 0; i < 64; ++i)
        ((float*)acc)[tid + 256 * i] = 0.0f;
    if (tid < CHUNK) idbuf[tid] = ids[t * S_SUP + ch * CHUNK + tid];
    __syncthreads();

    const ushortT* sb = se + ((long)t * S_SUP + ch * CHUNK) * D_EMB;
    #pragma unroll 4
    for (int s = 0; s < 64; ++s) {
        int row = half * 64 + s;
        int c = idbuf[row];
        acc[half][c][d] += b2f(sb[(long)row * D_EMB + d]);
    }
    __syncthreads();

    float* pb = psum + (long)blockIdx.x * N_WAY * D_EMB;
    #pragma unroll
    for (int i = 0; i < 32; ++i) {
        int idx = tid + 256 * i;
        pb[idx] = acc[0][idx >> 7][idx & 127] + acc[1][idx >> 7][idx & 127];
    }
    if (tid < N_WAY) {
        int cnt = 0;
        #pragma unroll 8
        for (int s = 0; s < CHUNK; ++s) cnt += (idbuf[s] == tid);
        pcnt[blockIdx.x * N_WAY + tid] = cnt;
    }
}

__global__ __launch_bounds__(256) void proto_reduce(
    const float* __restrict__ psum, const int* __restrict__ pcnt,
    float* __restrict__ protos)
{
    int idx = blockIdx.x * 256 + threadIdx.x;
    int t = idx >> 13;
    int cd = idx & 8191;
    int c = cd >> 7;

    float s = 0.0f;
    int cnt = 0;
    #pragma unroll
    for (int ch = 0; ch < NCHUNK; ++ch) {
        s   += psum[((long)(t * NCHUNK + ch)) * N_WAY * D_EMB + cd];
        cnt += pcnt[(t * NCHUNK + ch) * N_WAY + c];
    }
    protos[idx] = s / (float)(cnt > 0 ? cnt : 1);
}

// ---------------------------------------------------------------------------
// query_mfma: qe bf16 direct fragment loads.
// ---------------------------------------------------------------------------
__global__ __launch_bounds__(256) void query_mfma(
    const ushortT* __restrict__ qe, const float* __restrict__ qy,
    const float* __restrict__ protos_g, float* __restrict__ partials)
{
    __shared__ ushortT psA[N_WAY * D_EMB];       // [c][d] swizzled, 16 KiB
    __shared__ ushortT psT[D_EMB * N_WAY];       // [d][c] swizzled, 16 KiB
    __shared__ ushortT probs_s[4][16 * N_WAY];   // per-wave [q][c] swizzled, 8 KiB
    __shared__ float p2s[N_WAY];
    __shared__ float wloss[4];

    const int tid  = threadIdx.x;
    const int wave = tid >> 6;
    const int lane = tid & 63;
    const int lr   = lane & 15;
    const int lg   = lane >> 4;
    const int t    = blockIdx.x >> 5;        // 32 blocks per task
    const int qblk = blockIdx.x & 31;

    const float* pt = protos_g + (long)t * N_WAY * D_EMB;

    // ---- stage psA [c][d] bf16 swizzled + per-chunk sumsq for p2 --------
    float pp[4];
    #pragma unroll
    for (int i = 0; i < 4; ++i) {
        int ci = tid + 256 * i;
        int c = ci >> 4, col8 = (ci & 15) << 3;
        const float4* p = (const float4*)(pt + c * D_EMB + col8);
        float4 a = p[0], b = p[1];
        ushortT h0 = f2b(a.x), h1 = f2b(a.y), h2 = f2b(a.z), h3 = f2b(a.w);
        ushortT h4 = f2b(b.x), h5 = f2b(b.y), h6 = f2b(b.z), h7 = f2b(b.w);
        float ss = b2f(h0)*b2f(h0) + b2f(h1)*b2f(h1) + b2f(h2)*b2f(h2) + b2f(h3)*b2f(h3)
                 + b2f(h4)*b2f(h4) + b2f(h5)*b2f(h5) + b2f(h6)*b2f(h6) + b2f(h7)*b2f(h7);
        pp[i] = ss;
        uint4 v;
        v.x = (uintT)h0 | ((uintT)h1 << 16);
        v.y = (uintT)h2 | ((uintT)h3 << 16);
        v.z = (uintT)h4 | ((uintT)h5 << 16);
        v.w = (uintT)h6 | ((uintT)h7 << 16);
        int idx = c * D_EMB + col8;
        idx ^= (c & 7) << 3;
        *(uint4*)&psA[idx] = v;
    }
    #pragma unroll
    for (int off = 1; off < 16; off <<= 1) {
        #pragma unroll
        for (int i = 0; i < 4; ++i) pp[i] += __shfl_xor(pp[i], off);
    }
    if ((lane & 15) == 0) {
        int a = wave * 4 + (lane >> 4);
        #pragma unroll
        for (int i = 0; i < 4; ++i) p2s[a + 16 * i] = pp[i];
    }

    // ---- stage psT [d][c] bf16 swizzled ---------------------------------
    {
        int d  = wave * 32 + (lane & 31);
        int ch = lane >> 5;
        #pragma unroll
        for (int m = 0; m < 4; ++m) {
            ushortT hh[8];
            #pragma unroll
            for (int j = 0; j < 8; ++j)
                hh[j] = f2b(pt[(ch * 32 + m * 8 + j) * D_EMB + d]);
            uint4 v;
            v.x = (uintT)hh[0] | ((uintT)hh[1] << 16);
            v.y = (uintT)hh[2] | ((uintT)hh[3] << 16);
            v.z = (uintT)hh[4] | ((uintT)hh[5] << 16);
            v.w = (uintT)hh[6] | ((uintT)hh[7] << 16);
            int idx = d * N_WAY + ch * 32 + m * 8;
            idx ^= (d & 7) << 3;
            *(uint4*)&psT[idx] = v;
        }
    }
    __syncthreads();

    // ---- load qe rows as B-frags (bf16 direct), compute q2 --------------
    const long qrow = (long)t * Q_QRY + qblk * QB + wave * 16 + lr;
    bf16x8 bq[4];
    float q2 = 0.0f;
    #pragma unroll
    for (int kk = 0; kk < 4; ++kk) {
        bq[kk] = *(const bf16x8*)(qe + qrow * D_EMB + kk * 32 + lg * 8);
        #pragma unroll
        for (int j = 0; j < 8; ++j) {
            float v = b2f((ushortT)bq[kk][j]);
            q2 += v * v;
        }
    }
    q2 += __shfl_xor(q2, 16);
    q2 += __shfl_xor(q2, 32);

    // ---- qpT = protos . qe^T --------------------------------------------
    f32x4 acc[4];
    #pragma unroll
    for (int mt = 0; mt < 4; ++mt) { f32x4 z = {0,0,0,0}; acc[mt] = z; }
    #pragma unroll
    for (int kk = 0; kk < 4; ++kk) {
        #pragma unroll
        for (int mt = 0; mt < 4; ++mt) {
            int c = mt * 16 + lr;
            int idx = (c * D_EMB + kk * 32 + lg * 8) ^ ((c & 7) << 3);
            bf16x8 af = *(const bf16x8*)&psA[idx];
            acc[mt] = __builtin_amdgcn_mfma_f32_16x16x32_bf16(af, bq[kk], acc[mt], 0, 0, 0);
        }
    }

    // ---- dist -> in-register softmax over 64 classes --------------------
    float ev[4][4];
    float mx = -1e30f;
    #pragma unroll
    for (int mt = 0; mt < 4; ++mt) {
        #pragma unroll
        for (int r = 0; r < 4; ++r) {
            int c = mt * 16 + lg * 4 + r;
            float d2 = q2 + p2s[c] - 2.0f * acc[mt][r];
            float v = -sqrtf(fmaxf(d2, 0.0f));
            ev[mt][r] = v;
            mx = fmaxf(mx, v);
        }
    }
    mx = fmaxf(mx, __shfl_xor(mx, 16));
    mx = fmaxf(mx, __shfl_xor(mx, 32));
    float sum = 0.0f;
    #pragma unroll
    for (int mt = 0; mt < 4; ++mt)
        #pragma unroll
        for (int r = 0; r < 4; ++r) {
            float e = __expf(ev[mt][r] - mx);
            ev[mt][r] = e;
            sum += e;
        }
    sum += __shfl_xor(sum, 16);
    sum += __shfl_xor(sum, 32);
    float inv = 1.0f / sum;

    // ---- probs -> per-wave LDS tile [q][c] bf16 swizzled ----------------
    #pragma unroll
    for (int mt = 0; mt < 4; ++mt) {
        uintT lo = pk2(ev[mt][0] * inv, ev[mt][1] * inv);
        uintT hi = pk2(ev[mt][2] * inv, ev[mt][3] * inv);
        int idx = lr * N_WAY + ((mt * 16 + lg * 4) ^ ((lr & 7) << 3));
        uint2 v = {lo, hi};
        *(uint2*)&probs_s[wave][idx] = v;
    }

    // ---- pred = probs . protos ------------------------------------------
    f32x4 acc2[8];
    #pragma unroll
    for (int nt = 0; nt < 8; ++nt) { f32x4 z = {0,0,0,0}; acc2[nt] = z; }
    #pragma unroll
    for (int kk = 0; kk < 2; ++kk) {
        int idxa = lr * N_WAY + ((kk * 32 + lg * 8) ^ ((lr & 7) << 3));
        bf16x8 af = *(const bf16x8*)&probs_s[wave][idxa];
        #pragma unroll
        for (int nt = 0; nt < 8; ++nt) {
            int d = nt * 16 + lr;
            int idxb = (d * N_WAY + kk * 32 + lg * 8) ^ ((d & 7) << 3);
            bf16x8 bf = *(const bf16x8*)&psT[idxb];
            acc2[nt] = __builtin_amdgcn_mfma_f32_16x16x32_bf16(af, bf, acc2[nt], 0, 0, 0);
        }
    }

    // ---- fused squared-error loss ---------------------------------------
    float lossacc = 0.0f;
    const long qgbase = (long)t * Q_QRY + qblk * QB + wave * 16;
    #pragma unroll
    for (int r = 0; r < 4; ++r) {
        const float* yrow = qy + (qgbase + lg * 4 + r) * D_EMB;
        #pragma unroll
        for (int nt = 0; nt < 8; ++nt) {
            float diff = acc2[nt][r] - yrow[nt * 16 + lr];
            lossacc += diff * diff;
        }
    }
    #pragma unroll
    for (int off = 32; off >= 1; off >>= 1) lossacc += __shfl_xor(lossacc, off);
    if (lane == 0) wloss[wave] = lossacc;
    __syncthreads();
    if (tid == 0)
        partials[blockIdx.x] = wloss[0] + wloss[1] + wloss[2] + wloss[3];
}

// ---------------------------------------------------------------------------
// Final reduce: 512 partials -> meta_loss scalar
// ---------------------------------------------------------------------------
__global__ __launch_bounds__(256) void reduce_kernel(
    const float* __restrict__ partials, float* __restrict__ out)
{
    __shared__ float wsum[4];
    const int tid = threadIdx.x;
    float s = partials[tid] + partials[tid + 256];
    #pragma unroll
    for (int off = 32; off >= 1; off >>= 1) s += __shfl_xor(s, off);
    if ((tid & 63) == 0) wsum[tid >> 6] = s;
    __syncthreads();
    if (tid == 0) {
        const float inv = 1.0f / ((float)T_TASKS * Q_QRY * D_EMB);
        out[0] = (wsum[0] + wsum[1] + wsum[2] + wsum[3]) * inv;
    }
}

extern "C" void kernel_launch(void* const* d_in, const int* in_sizes, int n_in,
                              void* d_out, int out_size, void* d_ws, size_t ws_size,
                              hipStream_t stream)
{
    const float* support_x = (const float*)d_in[0];
    const int*   support_ids = (const int*)d_in[1];
    const float* query_x  = (const float*)d_in[2];
    const float* query_y  = (const float*)d_in[3];
    const float* W1 = (const float*)d_in[4];
    const float* b1 = (const float*)d_in[5];
    const float* W2 = (const float*)d_in[6];
    const float* b2 = (const float*)d_in[7];

    ushortT* se     = (ushortT*)d_ws;                            // 4.19M bf16
    ushortT* qe     = se + (long)T_TASKS * S_SUP * D_EMB;        // 4.19M bf16
    float* protos   = (float*)(qe + (long)T_TASKS * Q_QRY * D_EMB); // 131072 f
    float* partials = protos + T_TASKS * N_WAY * D_EMB;          // 1024
    ushortT* W1t    = (ushortT*)(partials + 1024);               // 512*256 bf16
    ushortT* W2t    = W1t + H_HID * D_IN;                        // 128*512 bf16
    float* psum     = (float*)(W2t + D_EMB * H_HID);             // 256*64*128 f
    int*   pcnt     = (int*)(psum + (long)T_TASKS * NCHUNK * N_WAY * D_EMB);

    convert_weights<<<512, 256, 0, stream>>>(W1, W2, W1t, W2t);
    embed_mfma4<<<1024, 512, 0, stream>>>(support_x, query_x, W1t, b1, W2t, b2, se, qe);
    proto_partial<<<T_TASKS * NCHUNK, 256, 0, stream>>>(se, support_ids, psum, pcnt);
    proto_reduce<<<512, 256, 0, stream>>>(psum, pcnt, protos);
    query_mfma<<<T_TASKS * (Q_QRY / QB), 256, 0, stream>>>(qe, query_y, protos, partials);
    reduce_kernel<<<1, 256, 0, stream>>>(partials, (float*)d_out);
}

// Round 11
// 144.249 us; speedup vs baseline: 1.3061x; 1.2399x over previous
//
#include <hip/hip_runtime.h>
#include <hip/hip_bf16.h>

#define T_TASKS 16
#define S_SUP   2048
#define Q_QRY   2048
#define D_IN    256
#define H_HID   512
#define D_EMB   128
#define N_WAY   64
#define NCHUNK  16
#define CHUNK   128   // S_SUP / NCHUNK
#define QB      64    // queries per block in query_mfma
#define BM4     64    // rows per block in embed_mfma6

typedef unsigned short ushortT;
typedef unsigned int uintT;
using bf16x8 = __attribute__((ext_vector_type(8))) short;
using f32x4  = __attribute__((ext_vector_type(4))) float;

__device__ __forceinline__ ushortT f2b(float f) {
    uintT u = __builtin_bit_cast(uintT, f);
    uintT r = u + 0x7FFFu + ((u >> 16) & 1u);   // round-to-nearest-even
    return (ushortT)(r >> 16);
}
__device__ __forceinline__ float b2f(ushortT h) {
    return __builtin_bit_cast(float, (uintT)h << 16);
}
__device__ __forceinline__ uintT pk2(float a, float b) {
    return (uintT)f2b(a) | ((uintT)f2b(b) << 16);
}

// ---------------------------------------------------------------------------
// Convert weights fp32 -> bf16, transposed to [N][K].
// ---------------------------------------------------------------------------
__global__ __launch_bounds__(256) void convert_weights(
    const float* __restrict__ W1, const float* __restrict__ W2,
    ushortT* __restrict__ W1t, ushortT* __restrict__ W2t)
{
    int i = blockIdx.x * 256 + threadIdx.x;
    if (i < D_IN * H_HID) {              // W1 [256][512] -> W1t [512][256]
        int k = i >> 9, n = i & 511;
        W1t[n * D_IN + k] = f2b(W1[i]);
    }
    if (i < H_HID * D_EMB) {             // W2 [512][128] -> W2t [128][512]
        int k = i >> 7, n = i & 127;
        W2t[n * H_HID + k] = f2b(W2[i]);
    }
}

// ---------------------------------------------------------------------------
// embed v6: swapped GEMMs (D = W . x^T -> b64 packed epilogues), register-safe.
// G1: identical to v4 (proven correct): 4 cgroups(128 cols) x 2 rgroups,
//     x B-frags reg-cached (bfc[2][8] = 64 VGPR, only live during G1).
// G2: STREAMED (v4's bhf[16] cache removed -> no spill): wave owns a
//     disjoint 16-col d-strip, all 64 rows; per kk: 1 W2t A-frag + 4 hs
//     B-frags (transient) + 4 MFMA. acc = 4 x f32x4 = 16 regs.
// ---------------------------------------------------------------------------
__global__ __launch_bounds__(512, 4) void embed_mfma6(
    const float* __restrict__ xa, const float* __restrict__ xb,
    const ushortT* __restrict__ W1t, const float* __restrict__ b1,
    const ushortT* __restrict__ W2t, const float* __restrict__ b2,
    ushortT* __restrict__ outa, ushortT* __restrict__ outb)
{
    __shared__ ushortT hs[BM4 * H_HID];   // 64 KiB; xs overlays first 32 KiB
    ushortT* xs = hs;                     // [64][256] swizzled (dead before hs)

    const int tid  = threadIdx.x;
    const int wid  = tid >> 6;
    const int lane = tid & 63;
    const int lr   = lane & 15;
    const int g    = lane >> 4;
    const int bid  = blockIdx.x;
    const float*  x   = (bid < 512) ? xa : xb;
    ushortT*      out = (bid < 512) ? outa : outb;
    const long rowbase = (long)(bid & 511) * BM4;

    // ---- stage x tile (64x256) as bf16 swizzled -------------------------
    #pragma unroll
    for (int i = 0; i < 4; ++i) {
        int ci   = tid + 512 * i;        // 2048 chunks of 8 elems
        int row  = ci >> 5;
        int col8 = (ci & 31) << 3;
        const float4* p = (const float4*)(x + (rowbase + row) * D_IN + col8);
        float4 a = p[0], b = p[1];
        uint4 v;
        v.x = pk2(a.x, a.y);
        v.y = pk2(a.z, a.w);
        v.z = pk2(b.x, b.y);
        v.w = pk2(b.z, b.w);
        int idx = (row << 8) + col8;
        idx ^= (row & 7) << 3;
        *(uint4*)&xs[idx] = v;
    }
    __syncthreads();

    // ---- cache x B-frags in regs (xs dead afterwards) -------------------
    const int rg1 = wid & 1;             // G1 row-group: rows rg1*32 .. +31
    const int cg1 = wid >> 1;            // G1 col-group: cols cg1*128 .. +127
    bf16x8 bfc[2][8];
    #pragma unroll
    for (int i = 0; i < 2; ++i) {
        int rl = rg1 * 32 + i * 16 + lr;
        #pragma unroll
        for (int kk = 0; kk < 8; ++kk) {
            int idx = (rl << 8) + kk * 32 + g * 8;
            idx ^= (rl & 7) << 3;
            bfc[i][kk] = *(const bf16x8*)&xs[idx];
        }
    }
    __syncthreads();   // xs reads complete -> hs may overwrite

    // ---- G1: D1[c][r] = W1t . x^T, relu, b64 LDS stores -----------------
    #pragma unroll
    for (int ct8 = 0; ct8 < 8; ++ct8) {
        int c0 = cg1 * 128 + ct8 * 16;
        float4 bv = *(const float4*)&b1[c0 + g * 4];
        f32x4 acc0 = {bv.x, bv.y, bv.z, bv.w};
        f32x4 acc1 = acc0;
        const ushortT* w1p = W1t + (c0 + lr) * D_IN + g * 8;
        #pragma unroll
        for (int kk = 0; kk < 8; ++kk) {
            bf16x8 af = *(const bf16x8*)(w1p + kk * 32);
            acc0 = __builtin_amdgcn_mfma_f32_16x16x32_bf16(af, bfc[0][kk], acc0, 0, 0, 0);
            acc1 = __builtin_amdgcn_mfma_f32_16x16x32_bf16(af, bfc[1][kk], acc1, 0, 0, 0);
        }
        // lane: row r = rg1*32 + i*16 + lr, cols c0+g*4 .. +3 (consecutive)
        uint2 u0, u1;
        u0.x = pk2(fmaxf(acc0[0], 0.f), fmaxf(acc0[1], 0.f));
        u0.y = pk2(fmaxf(acc0[2], 0.f), fmaxf(acc0[3], 0.f));
        u1.x = pk2(fmaxf(acc1[0], 0.f), fmaxf(acc1[1], 0.f));
        u1.y = pk2(fmaxf(acc1[2], 0.f), fmaxf(acc1[3], 0.f));
        int r0 = rg1 * 32 + lr;
        int i0 = ((r0)      * H_HID + c0 + g * 4) ^ (((r0)      & 7) << 3);
        int i1 = ((r0 + 16) * H_HID + c0 + g * 4) ^ (((r0 + 16) & 7) << 3);
        *(uint2*)&hs[i0] = u0;
        *(uint2*)&hs[i1] = u1;
    }
    __syncthreads();

    // ---- G2: D2[d][r] = W2t . h^T, streamed, b64 global stores ----------
    const int d0 = wid * 16;             // disjoint 16-col strip per wave
    f32x4 acc2[4];
    {
        float4 bv = *(const float4*)&b2[d0 + g * 4];
        f32x4 a = {bv.x, bv.y, bv.z, bv.w};
        #pragma unroll
        for (int rt = 0; rt < 4; ++rt) acc2[rt] = a;
    }
    {
        const ushortT* w2p = W2t + (d0 + lr) * H_HID + g * 8;
        #pragma unroll
        for (int kk = 0; kk < 16; ++kk) {
            bf16x8 aw = *(const bf16x8*)(w2p + kk * 32);
            #pragma unroll
            for (int rt = 0; rt < 4; ++rt) {
                int rl = rt * 16 + lr;
                int idx = (rl * H_HID + kk * 32 + g * 8) ^ ((rl & 7) << 3);
                bf16x8 bh = *(const bf16x8*)&hs[idx];
                acc2[rt] = __builtin_amdgcn_mfma_f32_16x16x32_bf16(aw, bh, acc2[rt], 0, 0, 0);
            }
        }
    }
    #pragma unroll
    for (int rt = 0; rt < 4; ++rt) {
        uint2 u;
        u.x = pk2(acc2[rt][0], acc2[rt][1]);
        u.y = pk2(acc2[rt][2], acc2[rt][3]);
        long row = rowbase + rt * 16 + lr;
        *(uint2*)&out[row * D_EMB + d0 + g * 4] = u;
    }
}

// ---------------------------------------------------------------------------
// Proto phase 1: block = (t, chunk of 128 rows), two LDS accumulation streams.
// ---------------------------------------------------------------------------
__global__ __launch_bounds__(256) void proto_partial(
    const ushortT* __restrict__ se, const int* __restrict__ ids,
    float* __restrict__ psum, int* __restrict__ pcnt)
{
    __shared__ float acc[2][N_WAY][D_EMB];  // 64 KiB
    __shared__ int idbuf[CHUNK];

    const int tid  = threadIdx.x;
    const int t    = blockIdx.x >> 4;
    const int ch   = blockIdx.x & 15;
    const int d    = tid & 127;
    const int half = tid >> 7;

    #pragma unroll
    for (int i = 0; i < 64; ++i)
        ((float*)acc)[tid + 256 * i] = 0.0f;
    if (tid < CHUNK) idbuf[tid] = ids[t * S_SUP + ch * CHUNK + tid];
    __syncthreads();

    const ushortT* sb = se + ((long)t * S_SUP + ch * CHUNK) * D_EMB;
    #pragma unroll 4
    for (int s = 0; s < 64; ++s) {
        int row = half * 64 + s;
        int c = idbuf[row];
        acc[half][c][d] += b2f(sb[(long)row * D_EMB + d]);
    }
    __syncthreads();

    float* pb = psum + (long)blockIdx.x * N_WAY * D_EMB;
    #pragma unroll
    for (int i = 0; i < 32; ++i) {
        int idx = tid + 256 * i;
        pb[idx] = acc[0][idx >> 7][idx & 127] + acc[1][idx >> 7][idx & 127];
    }
    if (tid < N_WAY) {
        int cnt = 0;
        #pragma unroll 8
        for (int s = 0; s < CHUNK; ++s) cnt += (idbuf[s] == tid);
        pcnt[blockIdx.x * N_WAY + tid] = cnt;
    }
}

__global__ __launch_bounds__(256) void proto_reduce(
    const float* __restrict__ psum, const int* __restrict__ pcnt,
    float* __restrict__ protos)
{
    int idx = blockIdx.x * 256 + threadIdx.x;
    int t = idx >> 13;
    int cd = idx & 8191;
    int c = cd >> 7;

    float s = 0.0f;
    int cnt = 0;
    #pragma unroll
    for (int ch = 0; ch < NCHUNK; ++ch) {
        s   += psum[((long)(t * NCHUNK + ch)) * N_WAY * D_EMB + cd];
        cnt += pcnt[(t * NCHUNK + ch) * N_WAY + c];
    }
    protos[idx] = s / (float)(cnt > 0 ? cnt : 1);
}

// ---------------------------------------------------------------------------
// query_mfma: qe bf16 direct fragment loads.
// ---------------------------------------------------------------------------
__global__ __launch_bounds__(256) void query_mfma(
    const ushortT* __restrict__ qe, const float* __restrict__ qy,
    const float* __restrict__ protos_g, float* __restrict__ partials)
{
    __shared__ ushortT psA[N_WAY * D_EMB];       // [c][d] swizzled, 16 KiB
    __shared__ ushortT psT[D_EMB * N_WAY];       // [d][c] swizzled, 16 KiB
    __shared__ ushortT probs_s[4][16 * N_WAY];   // per-wave [q][c] swizzled, 8 KiB
    __shared__ float p2s[N_WAY];
    __shared__ float wloss[4];

    const int tid  = threadIdx.x;
    const int wave = tid >> 6;
    const int lane = tid & 63;
    const int lr   = lane & 15;
    const int lg   = lane >> 4;
    const int t    = blockIdx.x >> 5;        // 32 blocks per task
    const int qblk = blockIdx.x & 31;

    const float* pt = protos_g + (long)t * N_WAY * D_EMB;

    // ---- stage psA [c][d] bf16 swizzled + per-chunk sumsq for p2 --------
    float pp[4];
    #pragma unroll
    for (int i = 0; i < 4; ++i) {
        int ci = tid + 256 * i;
        int c = ci >> 4, col8 = (ci & 15) << 3;
        const float4* p = (const float4*)(pt + c * D_EMB + col8);
        float4 a = p[0], b = p[1];
        ushortT h0 = f2b(a.x), h1 = f2b(a.y), h2 = f2b(a.z), h3 = f2b(a.w);
        ushortT h4 = f2b(b.x), h5 = f2b(b.y), h6 = f2b(b.z), h7 = f2b(b.w);
        float ss = b2f(h0)*b2f(h0) + b2f(h1)*b2f(h1) + b2f(h2)*b2f(h2) + b2f(h3)*b2f(h3)
                 + b2f(h4)*b2f(h4) + b2f(h5)*b2f(h5) + b2f(h6)*b2f(h6) + b2f(h7)*b2f(h7);
        pp[i] = ss;
        uint4 v;
        v.x = (uintT)h0 | ((uintT)h1 << 16);
        v.y = (uintT)h2 | ((uintT)h3 << 16);
        v.z = (uintT)h4 | ((uintT)h5 << 16);
        v.w = (uintT)h6 | ((uintT)h7 << 16);
        int idx = c * D_EMB + col8;
        idx ^= (c & 7) << 3;
        *(uint4*)&psA[idx] = v;
    }
    #pragma unroll
    for (int off = 1; off < 16; off <<= 1) {
        #pragma unroll
        for (int i = 0; i < 4; ++i) pp[i] += __shfl_xor(pp[i], off);
    }
    if ((lane & 15) == 0) {
        int a = wave * 4 + (lane >> 4);
        #pragma unroll
        for (int i = 0; i < 4; ++i) p2s[a + 16 * i] = pp[i];
    }

    // ---- stage psT [d][c] bf16 swizzled ---------------------------------
    {
        int d  = wave * 32 + (lane & 31);
        int ch = lane >> 5;
        #pragma unroll
        for (int m = 0; m < 4; ++m) {
            ushortT hh[8];
            #pragma unroll
            for (int j = 0; j < 8; ++j)
                hh[j] = f2b(pt[(ch * 32 + m * 8 + j) * D_EMB + d]);
            uint4 v;
            v.x = (uintT)hh[0] | ((uintT)hh[1] << 16);
            v.y = (uintT)hh[2] | ((uintT)hh[3] << 16);
            v.z = (uintT)hh[4] | ((uintT)hh[5] << 16);
            v.w = (uintT)hh[6] | ((uintT)hh[7] << 16);
            int idx = d * N_WAY + ch * 32 + m * 8;
            idx ^= (d & 7) << 3;
            *(uint4*)&psT[idx] = v;
        }
    }
    __syncthreads();

    // ---- load qe rows as B-frags (bf16 direct), compute q2 --------------
    const long qrow = (long)t * Q_QRY + qblk * QB + wave * 16 + lr;
    bf16x8 bq[4];
    float q2 = 0.0f;
    #pragma unroll
    for (int kk = 0; kk < 4; ++kk) {
        bq[kk] = *(const bf16x8*)(qe + qrow * D_EMB + kk * 32 + lg * 8);
        #pragma unroll
        for (int j = 0; j < 8; ++j) {
            float v = b2f((ushortT)bq[kk][j]);
            q2 += v * v;
        }
    }
    q2 += __shfl_xor(q2, 16);
    q2 += __shfl_xor(q2, 32);

    // ---- qpT = protos . qe^T --------------------------------------------
    f32x4 acc[4];
    #pragma unroll
    for (int mt = 0; mt < 4; ++mt) { f32x4 z = {0,0,0,0}; acc[mt] = z; }
    #pragma unroll
    for (int kk = 0; kk < 4; ++kk) {
        #pragma unroll
        for (int mt = 0; mt < 4; ++mt) {
            int c = mt * 16 + lr;
            int idx = (c * D_EMB + kk * 32 + lg * 8) ^ ((c & 7) << 3);
            bf16x8 af = *(const bf16x8*)&psA[idx];
            acc[mt] = __builtin_amdgcn_mfma_f32_16x16x32_bf16(af, bq[kk], acc[mt], 0, 0, 0);
        }
    }

    // ---- dist -> in-register softmax over 64 classes --------------------
    float ev[4][4];
    float mx = -1e30f;
    #pragma unroll
    for (int mt = 0; mt < 4; ++mt) {
        #pragma unroll
        for (int r = 0; r < 4; ++r) {
            int c = mt * 16 + lg * 4 + r;
            float d2 = q2 + p2s[c] - 2.0f * acc[mt][r];
            float v = -sqrtf(fmaxf(d2, 0.0f));
            ev[mt][r] = v;
            mx = fmaxf(mx, v);
        }
    }
    mx = fmaxf(mx, __shfl_xor(mx, 16));
    mx = fmaxf(mx, __shfl_xor(mx, 32));
    float sum = 0.0f;
    #pragma unroll
    for (int mt = 0; mt < 4; ++mt)
        #pragma unroll
        for (int r = 0; r < 4; ++r) {
            float e = __expf(ev[mt][r] - mx);
            ev[mt][r] = e;
            sum += e;
        }
    sum += __shfl_xor(sum, 16);
    sum += __shfl_xor(sum, 32);
    float inv = 1.0f / sum;

    // ---- probs -> per-wave LDS tile [q][c] bf16 swizzled ----------------
    #pragma unroll
    for (int mt = 0; mt < 4; ++mt) {
        uintT lo = pk2(ev[mt][0] * inv, ev[mt][1] * inv);
        uintT hi = pk2(ev[mt][2] * inv, ev[mt][3] * inv);
        int idx = lr * N_WAY + ((mt * 16 + lg * 4) ^ ((lr & 7) << 3));
        uint2 v = {lo, hi};
        *(uint2*)&probs_s[wave][idx] = v;
    }

    // ---- pred = probs . protos ------------------------------------------
    f32x4 acc2[8];
    #pragma unroll
    for (int nt = 0; nt < 8; ++nt) { f32x4 z = {0,0,0,0}; acc2[nt] = z; }
    #pragma unroll
    for (int kk = 0; kk < 2; ++kk) {
        int idxa = lr * N_WAY + ((kk * 32 + lg * 8) ^ ((lr & 7) << 3));
        bf16x8 af = *(const bf16x8*)&probs_s[wave][idxa];
        #pragma unroll
        for (int nt = 0; nt < 8; ++nt) {
            int d = nt * 16 + lr;
            int idxb = (d * N_WAY + kk * 32 + lg * 8) ^ ((d & 7) << 3);
            bf16x8 bf = *(const bf16x8*)&psT[idxb];
            acc2[nt] = __builtin_amdgcn_mfma_f32_16x16x32_bf16(af, bf, acc2[nt], 0, 0, 0);
        }
    }

    // ---- fused squared-error loss ---------------------------------------
    float lossacc = 0.0f;
    const long qgbase = (long)t * Q_QRY + qblk * QB + wave * 16;
    #pragma unroll
    for (int r = 0; r < 4; ++r) {
        const float* yrow = qy + (qgbase + lg * 4 + r) * D_EMB;
        #pragma unroll
        for (int nt = 0; nt < 8; ++nt) {
            float diff = acc2[nt][r] - yrow[nt * 16 + lr];
            lossacc += diff * diff;
        }
    }
    #pragma unroll
    for (int off = 32; off >= 1; off >>= 1) lossacc += __shfl_xor(lossacc, off);
    if (lane == 0) wloss[wave] = lossacc;
    __syncthreads();
    if (tid == 0)
        partials[blockIdx.x] = wloss[0] + wloss[1] + wloss[2] + wloss[3];
}

// ---------------------------------------------------------------------------
// Final reduce: 512 partials -> meta_loss scalar
// ---------------------------------------------------------------------------
__global__ __launch_bounds__(256) void reduce_kernel(
    const float* __restrict__ partials, float* __restrict__ out)
{
    __shared__ float wsum[4];
    const int tid = threadIdx.x;
    float s = partials[tid] + partials[tid + 256];
    #pragma unroll
    for (int off = 32; off >= 1; off >>= 1) s += __shfl_xor(s, off);
    if ((tid & 63) == 0) wsum[tid >> 6] = s;
    __syncthreads();
    if (tid == 0) {
        const float inv = 1.0f / ((float)T_TASKS * Q_QRY * D_EMB);
        out[0] = (wsum[0] + wsum[1] + wsum[2] + wsum[3]) * inv;
    }
}

extern "C" void kernel_launch(void* const* d_in, const int* in_sizes, int n_in,
                              void* d_out, int out_size, void* d_ws, size_t ws_size,
                              hipStream_t stream)
{
    const float* support_x = (const float*)d_in[0];
    const int*   support_ids = (const int*)d_in[1];
    const float* query_x  = (const float*)d_in[2];
    const float* query_y  = (const float*)d_in[3];
    const float* W1 = (const float*)d_in[4];
    const float* b1 = (const float*)d_in[5];
    const float* W2 = (const float*)d_in[6];
    const float* b2 = (const float*)d_in[7];

    ushortT* se     = (ushortT*)d_ws;                            // 4.19M bf16
    ushortT* qe     = se + (long)T_TASKS * S_SUP * D_EMB;        // 4.19M bf16
    float* protos   = (float*)(qe + (long)T_TASKS * Q_QRY * D_EMB); // 131072 f
    float* partials = protos + T_TASKS * N_WAY * D_EMB;          // 1024
    ushortT* W1t    = (ushortT*)(partials + 1024);               // 512*256 bf16
    ushortT* W2t    = W1t + H_HID * D_IN;                        // 128*512 bf16
    float* psum     = (float*)(W2t + D_EMB * H_HID);             // 256*64*128 f
    int*   pcnt     = (int*)(psum + (long)T_TASKS * NCHUNK * N_WAY * D_EMB);

    convert_weights<<<512, 256, 0, stream>>>(W1, W2, W1t, W2t);
    embed_mfma6<<<1024, 512, 0, stream>>>(support_x, query_x, W1t, b1, W2t, b2, se, qe);
    proto_partial<<<T_TASKS * NCHUNK, 256, 0, stream>>>(se, support_ids, psum, pcnt);
    proto_reduce<<<512, 256, 0, stream>>>(psum, pcnt, protos);
    query_mfma<<<T_TASKS * (Q_QRY / QB), 256, 0, stream>>>(qe, query_y, protos, partials);
    reduce_kernel<<<1, 256, 0, stream>>>(partials, (float*)d_out);
}

// Round 12
// 87.246 us; speedup vs baseline: 2.1595x; 1.6534x over previous
//
#include <hip/hip_runtime.h>
#include <hip/hip_bf16.h>

#define T_TASKS 16
#define S_SUP   2048
#define Q_QRY   2048
#define D_IN    256
#define H_HID   512
#define D_EMB   128
#define N_WAY   64
#define NCHUNK  16
#define CHUNK   128   // S_SUP / NCHUNK
#define QB      64    // queries per block in query_mfma
#define BM4     64    // rows per block in embed_mfma7

typedef unsigned short ushortT;
typedef unsigned int uintT;
using bf16x8 = __attribute__((ext_vector_type(8))) short;
using f32x4  = __attribute__((ext_vector_type(4))) float;

__device__ __forceinline__ ushortT f2b(float f) {
    uintT u = __builtin_bit_cast(uintT, f);
    uintT r = u + 0x7FFFu + ((u >> 16) & 1u);   // round-to-nearest-even
    return (ushortT)(r >> 16);
}
__device__ __forceinline__ float b2f(ushortT h) {
    return __builtin_bit_cast(float, (uintT)h << 16);
}
__device__ __forceinline__ uintT pk2(float a, float b) {
    return (uintT)f2b(a) | ((uintT)f2b(b) << 16);
}

// ---------------------------------------------------------------------------
// Convert weights fp32 -> bf16, transposed to [N][K].
// ---------------------------------------------------------------------------
__global__ __launch_bounds__(256) void convert_weights(
    const float* __restrict__ W1, const float* __restrict__ W2,
    ushortT* __restrict__ W1t, ushortT* __restrict__ W2t)
{
    int i = blockIdx.x * 256 + threadIdx.x;
    if (i < D_IN * H_HID) {              // W1 [256][512] -> W1t [512][256]
        int k = i >> 9, n = i & 511;
        W1t[n * D_IN + k] = f2b(W1[i]);
    }
    if (i < H_HID * D_EMB) {             // W2 [512][128] -> W2t [128][512]
        int k = i >> 7, n = i & 127;
        W2t[n * H_HID + k] = f2b(W2[i]);
    }
}

// ---------------------------------------------------------------------------
// embed v7: swapped GEMMs (D = W . x^T -> b64 packed epilogues) with
// round-5's PROVEN register profile (no B-frag register cache -> no spill).
// 512 thr (8 waves), 64 rows/block, 64 KiB LDS (xs overlays hs), 1 dispatch.
// G1 (kk-outer): wave owns 64-col c-strip x all 64 rows; acc[4][4] = 64 regs.
//   per kk: 4 xs ds_read_b128 + 4 W1t global b128 + 16 MFMA.
// G2 (streamed): wave owns 16-col d-strip x all 64 rows; acc2[4] = 16 regs.
// ---------------------------------------------------------------------------
__global__ __launch_bounds__(512, 4) void embed_mfma7(
    const float* __restrict__ xa, const float* __restrict__ xb,
    const ushortT* __restrict__ W1t, const float* __restrict__ b1,
    const ushortT* __restrict__ W2t, const float* __restrict__ b2,
    ushortT* __restrict__ outa, ushortT* __restrict__ outb)
{
    __shared__ ushortT hs[BM4 * H_HID];   // 64 KiB; xs overlays first 32 KiB
    ushortT* xs = hs;                     // [64][256] swizzled (dead before hs)

    const int tid  = threadIdx.x;
    const int wid  = tid >> 6;
    const int lane = tid & 63;
    const int lr   = lane & 15;
    const int g    = lane >> 4;
    const int bid  = blockIdx.x;
    const float*  x   = (bid < 512) ? xa : xb;
    ushortT*      out = (bid < 512) ? outa : outb;
    const long rowbase = (long)(bid & 511) * BM4;

    // ---- stage x tile (64x256) as bf16 swizzled -------------------------
    #pragma unroll
    for (int i = 0; i < 4; ++i) {
        int ci   = tid + 512 * i;        // 2048 chunks of 8 elems
        int row  = ci >> 5;
        int col8 = (ci & 31) << 3;
        const float4* p = (const float4*)(x + (rowbase + row) * D_IN + col8);
        float4 a = p[0], b = p[1];
        uint4 v;
        v.x = pk2(a.x, a.y);
        v.y = pk2(a.z, a.w);
        v.z = pk2(b.x, b.y);
        v.w = pk2(b.z, b.w);
        int idx = (row << 8) + col8;
        idx ^= (row & 7) << 3;
        *(uint4*)&xs[idx] = v;
    }
    __syncthreads();

    // ---- G1: D1[c][r] = W1t . x^T, kk-outer, acc[ct][rt] ----------------
    const int c0w = wid * 64;            // wave's 64-col strip
    f32x4 acc[4][4];                     // [c-tile][r-tile] = 64 regs
    #pragma unroll
    for (int ct = 0; ct < 4; ++ct) {
        float4 bv = *(const float4*)&b1[c0w + ct * 16 + g * 4];
        f32x4 a = {bv.x, bv.y, bv.z, bv.w};
        #pragma unroll
        for (int rt = 0; rt < 4; ++rt) acc[ct][rt] = a;
    }
    {
        const ushortT* w1p = W1t + (c0w + lr) * D_IN + g * 8;
        #pragma unroll
        for (int kk = 0; kk < 8; ++kk) {
            bf16x8 xf[4];
            #pragma unroll
            for (int rt = 0; rt < 4; ++rt) {
                int rl = rt * 16 + lr;
                int idx = ((rl << 8) + kk * 32 + g * 8) ^ ((rl & 7) << 3);
                xf[rt] = *(const bf16x8*)&xs[idx];
            }
            #pragma unroll
            for (int ct = 0; ct < 4; ++ct) {
                bf16x8 wf = *(const bf16x8*)(w1p + ct * 16 * D_IN + kk * 32);
                #pragma unroll
                for (int rt = 0; rt < 4; ++rt)
                    acc[ct][rt] = __builtin_amdgcn_mfma_f32_16x16x32_bf16(wf, xf[rt], acc[ct][rt], 0, 0, 0);
            }
        }
    }
    __syncthreads();   // all xs reads complete -> hs may overwrite

    // ---- G1 epilogue: relu -> b64 swizzled LDS stores -------------------
    #pragma unroll
    for (int ct = 0; ct < 4; ++ct)
        #pragma unroll
        for (int rt = 0; rt < 4; ++rt) {
            uint2 u;
            u.x = pk2(fmaxf(acc[ct][rt][0], 0.f), fmaxf(acc[ct][rt][1], 0.f));
            u.y = pk2(fmaxf(acc[ct][rt][2], 0.f), fmaxf(acc[ct][rt][3], 0.f));
            int r = rt * 16 + lr;
            int c = c0w + ct * 16 + g * 4;
            int idx = (r * H_HID + c) ^ ((r & 7) << 3);
            *(uint2*)&hs[idx] = u;
        }
    __syncthreads();

    // ---- G2: D2[d][r] = W2t . h^T, streamed, b64 global stores ----------
    const int d0 = wid * 16;             // disjoint 16-col strip per wave
    f32x4 acc2[4];
    {
        float4 bv = *(const float4*)&b2[d0 + g * 4];
        f32x4 a = {bv.x, bv.y, bv.z, bv.w};
        #pragma unroll
        for (int rt = 0; rt < 4; ++rt) acc2[rt] = a;
    }
    {
        const ushortT* w2p = W2t + (d0 + lr) * H_HID + g * 8;
        #pragma unroll
        for (int kk = 0; kk < 16; ++kk) {
            bf16x8 aw = *(const bf16x8*)(w2p + kk * 32);
            #pragma unroll
            for (int rt = 0; rt < 4; ++rt) {
                int rl = rt * 16 + lr;
                int idx = (rl * H_HID + kk * 32 + g * 8) ^ ((rl & 7) << 3);
                bf16x8 bh = *(const bf16x8*)&hs[idx];
                acc2[rt] = __builtin_amdgcn_mfma_f32_16x16x32_bf16(aw, bh, acc2[rt], 0, 0, 0);
            }
        }
    }
    #pragma unroll
    for (int rt = 0; rt < 4; ++rt) {
        uint2 u;
        u.x = pk2(acc2[rt][0], acc2[rt][1]);
        u.y = pk2(acc2[rt][2], acc2[rt][3]);
        long row = rowbase + rt * 16 + lr;
        *(uint2*)&out[row * D_EMB + d0 + g * 4] = u;
    }
}

// ---------------------------------------------------------------------------
// Proto phase 1: block = (t, chunk of 128 rows), two LDS accumulation streams.
// ---------------------------------------------------------------------------
__global__ __launch_bounds__(256) void proto_partial(
    const ushortT* __restrict__ se, const int* __restrict__ ids,
    float* __restrict__ psum, int* __restrict__ pcnt)
{
    __shared__ float acc[2][N_WAY][D_EMB];  // 64 KiB
    __shared__ int idbuf[CHUNK];

    const int tid  = threadIdx.x;
    const int t    = blockIdx.x >> 4;
    const int ch   = blockIdx.x & 15;
    const int d    = tid & 127;
    const int half = tid >> 7;

    #pragma unroll
    for (int i = 0; i < 64; ++i)
        ((float*)acc)[tid + 256 * i] = 0.0f;
    if (tid < CHUNK) idbuf[tid] = ids[t * S_SUP + ch * CHUNK + tid];
    __syncthreads();

    const ushortT* sb = se + ((long)t * S_SUP + ch * CHUNK) * D_EMB;
    #pragma unroll 4
    for (int s = 0; s < 64; ++s) {
        int row = half * 64 + s;
        int c = idbuf[row];
        acc[half][c][d] += b2f(sb[(long)row * D_EMB + d]);
    }
    __syncthreads();

    float* pb = psum + (long)blockIdx.x * N_WAY * D_EMB;
    #pragma unroll
    for (int i = 0; i < 32; ++i) {
        int idx = tid + 256 * i;
        pb[idx] = acc[0][idx >> 7][idx & 127] + acc[1][idx >> 7][idx & 127];
    }
    if (tid < N_WAY) {
        int cnt = 0;
        #pragma unroll 8
        for (int s = 0; s < CHUNK; ++s) cnt += (idbuf[s] == tid);
        pcnt[blockIdx.x * N_WAY + tid] = cnt;
    }
}

__global__ __launch_bounds__(256) void proto_reduce(
    const float* __restrict__ psum, const int* __restrict__ pcnt,
    float* __restrict__ protos)
{
    int idx = blockIdx.x * 256 + threadIdx.x;
    int t = idx >> 13;
    int cd = idx & 8191;
    int c = cd >> 7;

    float s = 0.0f;
    int cnt = 0;
    #pragma unroll
    for (int ch = 0; ch < NCHUNK; ++ch) {
        s   += psum[((long)(t * NCHUNK + ch)) * N_WAY * D_EMB + cd];
        cnt += pcnt[(t * NCHUNK + ch) * N_WAY + c];
    }
    protos[idx] = s / (float)(cnt > 0 ? cnt : 1);
}

// ---------------------------------------------------------------------------
// query_mfma: qe bf16 direct fragment loads.
// ---------------------------------------------------------------------------
__global__ __launch_bounds__(256) void query_mfma(
    const ushortT* __restrict__ qe, const float* __restrict__ qy,
    const float* __restrict__ protos_g, float* __restrict__ partials)
{
    __shared__ ushortT psA[N_WAY * D_EMB];       // [c][d] swizzled, 16 KiB
    __shared__ ushortT psT[D_EMB * N_WAY];       // [d][c] swizzled, 16 KiB
    __shared__ ushortT probs_s[4][16 * N_WAY];   // per-wave [q][c] swizzled, 8 KiB
    __shared__ float p2s[N_WAY];
    __shared__ float wloss[4];

    const int tid  = threadIdx.x;
    const int wave = tid >> 6;
    const int lane = tid & 63;
    const int lr   = lane & 15;
    const int lg   = lane >> 4;
    const int t    = blockIdx.x >> 5;        // 32 blocks per task
    const int qblk = blockIdx.x & 31;

    const float* pt = protos_g + (long)t * N_WAY * D_EMB;

    // ---- stage psA [c][d] bf16 swizzled + per-chunk sumsq for p2 --------
    float pp[4];
    #pragma unroll
    for (int i = 0; i < 4; ++i) {
        int ci = tid + 256 * i;
        int c = ci >> 4, col8 = (ci & 15) << 3;
        const float4* p = (const float4*)(pt + c * D_EMB + col8);
        float4 a = p[0], b = p[1];
        ushortT h0 = f2b(a.x), h1 = f2b(a.y), h2 = f2b(a.z), h3 = f2b(a.w);
        ushortT h4 = f2b(b.x), h5 = f2b(b.y), h6 = f2b(b.z), h7 = f2b(b.w);
        float ss = b2f(h0)*b2f(h0) + b2f(h1)*b2f(h1) + b2f(h2)*b2f(h2) + b2f(h3)*b2f(h3)
                 + b2f(h4)*b2f(h4) + b2f(h5)*b2f(h5) + b2f(h6)*b2f(h6) + b2f(h7)*b2f(h7);
        pp[i] = ss;
        uint4 v;
        v.x = (uintT)h0 | ((uintT)h1 << 16);
        v.y = (uintT)h2 | ((uintT)h3 << 16);
        v.z = (uintT)h4 | ((uintT)h5 << 16);
        v.w = (uintT)h6 | ((uintT)h7 << 16);
        int idx = c * D_EMB + col8;
        idx ^= (c & 7) << 3;
        *(uint4*)&psA[idx] = v;
    }
    #pragma unroll
    for (int off = 1; off < 16; off <<= 1) {
        #pragma unroll
        for (int i = 0; i < 4; ++i) pp[i] += __shfl_xor(pp[i], off);
    }
    if ((lane & 15) == 0) {
        int a = wave * 4 + (lane >> 4);
        #pragma unroll
        for (int i = 0; i < 4; ++i) p2s[a + 16 * i] = pp[i];
    }

    // ---- stage psT [d][c] bf16 swizzled ---------------------------------
    {
        int d  = wave * 32 + (lane & 31);
        int ch = lane >> 5;
        #pragma unroll
        for (int m = 0; m < 4; ++m) {
            ushortT hh[8];
            #pragma unroll
            for (int j = 0; j < 8; ++j)
                hh[j] = f2b(pt[(ch * 32 + m * 8 + j) * D_EMB + d]);
            uint4 v;
            v.x = (uintT)hh[0] | ((uintT)hh[1] << 16);
            v.y = (uintT)hh[2] | ((uintT)hh[3] << 16);
            v.z = (uintT)hh[4] | ((uintT)hh[5] << 16);
            v.w = (uintT)hh[6] | ((uintT)hh[7] << 16);
            int idx = d * N_WAY + ch * 32 + m * 8;
            idx ^= (d & 7) << 3;
            *(uint4*)&psT[idx] = v;
        }
    }
    __syncthreads();

    // ---- load qe rows as B-frags (bf16 direct), compute q2 --------------
    const long qrow = (long)t * Q_QRY + qblk * QB + wave * 16 + lr;
    bf16x8 bq[4];
    float q2 = 0.0f;
    #pragma unroll
    for (int kk = 0; kk < 4; ++kk) {
        bq[kk] = *(const bf16x8*)(qe + qrow * D_EMB + kk * 32 + lg * 8);
        #pragma unroll
        for (int j = 0; j < 8; ++j) {
            float v = b2f((ushortT)bq[kk][j]);
            q2 += v * v;
        }
    }
    q2 += __shfl_xor(q2, 16);
    q2 += __shfl_xor(q2, 32);

    // ---- qpT = protos . qe^T --------------------------------------------
    f32x4 acc[4];
    #pragma unroll
    for (int mt = 0; mt < 4; ++mt) { f32x4 z = {0,0,0,0}; acc[mt] = z; }
    #pragma unroll
    for (int kk = 0; kk < 4; ++kk) {
        #pragma unroll
        for (int mt = 0; mt < 4; ++mt) {
            int c = mt * 16 + lr;
            int idx = (c * D_EMB + kk * 32 + lg * 8) ^ ((c & 7) << 3);
            bf16x8 af = *(const bf16x8*)&psA[idx];
            acc[mt] = __builtin_amdgcn_mfma_f32_16x16x32_bf16(af, bq[kk], acc[mt], 0, 0, 0);
        }
    }

    // ---- dist -> in-register softmax over 64 classes --------------------
    float ev[4][4];
    float mx = -1e30f;
    #pragma unroll
    for (int mt = 0; mt < 4; ++mt) {
        #pragma unroll
        for (int r = 0; r < 4; ++r) {
            int c = mt * 16 + lg * 4 + r;
            float d2 = q2 + p2s[c] - 2.0f * acc[mt][r];
            float v = -sqrtf(fmaxf(d2, 0.0f));
            ev[mt][r] = v;
            mx = fmaxf(mx, v);
        }
    }
    mx = fmaxf(mx, __shfl_xor(mx, 16));
    mx = fmaxf(mx, __shfl_xor(mx, 32));
    float sum = 0.0f;
    #pragma unroll
    for (int mt = 0; mt < 4; ++mt)
        #pragma unroll
        for (int r = 0; r < 4; ++r) {
            float e = __expf(ev[mt][r] - mx);
            ev[mt][r] = e;
            sum += e;
        }
    sum += __shfl_xor(sum, 16);
    sum += __shfl_xor(sum, 32);
    float inv = 1.0f / sum;

    // ---- probs -> per-wave LDS tile [q][c] bf16 swizzled ----------------
    #pragma unroll
    for (int mt = 0; mt < 4; ++mt) {
        uintT lo = pk2(ev[mt][0] * inv, ev[mt][1] * inv);
        uintT hi = pk2(ev[mt][2] * inv, ev[mt][3] * inv);
        int idx = lr * N_WAY + ((mt * 16 + lg * 4) ^ ((lr & 7) << 3));
        uint2 v = {lo, hi};
        *(uint2*)&probs_s[wave][idx] = v;
    }

    // ---- pred = probs . protos ------------------------------------------
    f32x4 acc2[8];
    #pragma unroll
    for (int nt = 0; nt < 8; ++nt) { f32x4 z = {0,0,0,0}; acc2[nt] = z; }
    #pragma unroll
    for (int kk = 0; kk < 2; ++kk) {
        int idxa = lr * N_WAY + ((kk * 32 + lg * 8) ^ ((lr & 7) << 3));
        bf16x8 af = *(const bf16x8*)&probs_s[wave][idxa];
        #pragma unroll
        for (int nt = 0; nt < 8; ++nt) {
            int d = nt * 16 + lr;
            int idxb = (d * N_WAY + kk * 32 + lg * 8) ^ ((d & 7) << 3);
            bf16x8 bf = *(const bf16x8*)&psT[idxb];
            acc2[nt] = __builtin_amdgcn_mfma_f32_16x16x32_bf16(af, bf, acc2[nt], 0, 0, 0);
        }
    }

    // ---- fused squared-error loss ---------------------------------------
    float lossacc = 0.0f;
    const long qgbase = (long)t * Q_QRY + qblk * QB + wave * 16;
    #pragma unroll
    for (int r = 0; r < 4; ++r) {
        const float* yrow = qy + (qgbase + lg * 4 + r) * D_EMB;
        #pragma unroll
        for (int nt = 0; nt < 8; ++nt) {
            float diff = acc2[nt][r] - yrow[nt * 16 + lr];
            lossacc += diff * diff;
        }
    }
    #pragma unroll
    for (int off = 32; off >= 1; off >>= 1) lossacc += __shfl_xor(lossacc, off);
    if (lane == 0) wloss[wave] = lossacc;
    __syncthreads();
    if (tid == 0)
        partials[blockIdx.x] = wloss[0] + wloss[1] + wloss[2] + wloss[3];
}

// ---------------------------------------------------------------------------
// Final reduce: 512 partials -> meta_loss scalar
// ---------------------------------------------------------------------------
__global__ __launch_bounds__(256) void reduce_kernel(
    const float* __restrict__ partials, float* __restrict__ out)
{
    __shared__ float wsum[4];
    const int tid = threadIdx.x;
    float s = partials[tid] + partials[tid + 256];
    #pragma unroll
    for (int off = 32; off >= 1; off >>= 1) s += __shfl_xor(s, off);
    if ((tid & 63) == 0) wsum[tid >> 6] = s;
    __syncthreads();
    if (tid == 0) {
        const float inv = 1.0f / ((float)T_TASKS * Q_QRY * D_EMB);
        out[0] = (wsum[0] + wsum[1] + wsum[2] + wsum[3]) * inv;
    }
}

extern "C" void kernel_launch(void* const* d_in, const int* in_sizes, int n_in,
                              void* d_out, int out_size, void* d_ws, size_t ws_size,
                              hipStream_t stream)
{
    const float* support_x = (const float*)d_in[0];
    const int*   support_ids = (const int*)d_in[1];
    const float* query_x  = (const float*)d_in[2];
    const float* query_y  = (const float*)d_in[3];
    const float* W1 = (const float*)d_in[4];
    const float* b1 = (const float*)d_in[5];
    const float* W2 = (const float*)d_in[6];
    const float* b2 = (const float*)d_in[7];

    ushortT* se     = (ushortT*)d_ws;                            // 4.19M bf16
    ushortT* qe     = se + (long)T_TASKS * S_SUP * D_EMB;        // 4.19M bf16
    float* protos   = (float*)(qe + (long)T_TASKS * Q_QRY * D_EMB); // 131072 f
    float* partials = protos + T_TASKS * N_WAY * D_EMB;          // 1024
    ushortT* W1t    = (ushortT*)(partials + 1024);               // 512*256 bf16
    ushortT* W2t    = W1t + H_HID * D_IN;                        // 128*512 bf16
    float* psum     = (float*)(W2t + D_EMB * H_HID);             // 256*64*128 f
    int*   pcnt     = (int*)(psum + (long)T_TASKS * NCHUNK * N_WAY * D_EMB);

    convert_weights<<<512, 256, 0, stream>>>(W1, W2, W1t, W2t);
    embed_mfma7<<<1024, 512, 0, stream>>>(support_x, query_x, W1t, b1, W2t, b2, se, qe);
    proto_partial<<<T_TASKS * NCHUNK, 256, 0, stream>>>(se, support_ids, psum, pcnt);
    proto_reduce<<<512, 256, 0, stream>>>(psum, pcnt, protos);
    query_mfma<<<T_TASKS * (Q_QRY / QB), 256, 0, stream>>>(qe, query_y, protos, partials);
    reduce_kernel<<<1, 256, 0, stream>>>(partials, (float*)d_out);
}